// Round 16
// baseline (230.696 us; speedup 1.0000x reference)
//
#include <hip/hip_runtime.h>
#include <math.h>

#define LUTN 1024
#define LUTSCALE 512.0f
#define NBINS 50048        // >= N, multiple of 4 (uchar-packed LDS histogram width)
#define CHSH 14            // edge chunk = 16384 edges per histogram block pair (P=31)
                           // per-chunk per-bin count ~Poisson(0.33), max ~8 << 255: uchar safe

// ---------------- K1: front — fused roles: hist blocks [0,2P) + prep blocks [2P,2P+PREPB) ---
// hist role: block 2p = dst hist + rank of chunk p -> pcnt/rnk8; 2p+1 = src hist -> psrc.
// prep role: M table, LUT, feat->bf16, loc->float4. Independent inputs, no cross-role deps.

__global__ __launch_bounds__(512) void front_kernel(
    const float* __restrict__ embed, const float* __restrict__ G_w,
    const float* __restrict__ boundaries, const float* __restrict__ feat,
    const float* __restrict__ loc,
    const int* __restrict__ src, const int* __restrict__ dst,
    float* __restrict__ M, int* __restrict__ lut,
    unsigned short* __restrict__ featH, float4* __restrict__ loc4,
    unsigned char* __restrict__ pcnt, unsigned char* __restrict__ psrc,
    unsigned char* __restrict__ rnk8,
    int N, int E, int P, int PREPB) {

    __shared__ unsigned int h[NBINS / 4];   // 50 KB (hist roles only; prep ignores)

    if (blockIdx.x < 2 * P) {
        for (int i = threadIdx.x; i < NBINS / 4; i += 512) h[i] = 0u;
        __syncthreads();

        const int p    = blockIdx.x >> 1;
        const int role = blockIdx.x & 1;
        const int base = p << CHSH;
        const int lim  = min(E - base, 1 << CHSH);

        if (role == 0) {
            for (int t = threadIdx.x; t < lim; t += 512) {
                const int e = base + t;
                const int d = dst[e];
                const unsigned sh = (unsigned)(d & 3) * 8u;
                unsigned old = atomicAdd(&h[d >> 2], 1u << sh);
                rnk8[e] = (unsigned char)((old >> sh) & 0xFFu);
            }
            __syncthreads();
            unsigned int* gc = (unsigned int*)(pcnt + (size_t)p * NBINS);
            for (int i = threadIdx.x; i < NBINS / 4; i += 512) gc[i] = h[i];
        } else {
            for (int t = threadIdx.x; t < lim; t += 512) {
                const int s = src[base + t];
                atomicAdd(&h[s >> 2], 1u << ((unsigned)(s & 3) * 8u));
            }
            __syncthreads();
            unsigned int* gs = (unsigned int*)(psrc + (size_t)p * NBINS);
            for (int i = threadIdx.x; i < NBINS / 4; i += 512) gs[i] = h[i];
        }
        return;
    }

    // ---- prep role ----
    const int gid = (blockIdx.x - 2 * P) * 512 + threadIdx.x;
    const int gsz = PREPB * 512;
    for (int i = gid; i < 4096; i += gsz) {
        int b = i >> 6, f = i & 63;
        float acc = 0.f;
        #pragma unroll
        for (int dd = 0; dd < 32; ++dd) acc += embed[b * 32 + dd] * G_w[f * 32 + dd];
        M[i] = acc;
    }
    for (int i = gid; i < LUTN; i += gsz) {
        float left = (float)i * (1.0f / LUTSCALE);
        int c = 0;
        for (int j = 0; j < 63; ++j) c += (boundaries[j] < left) ? 1 : 0;
        lut[i] = c;
    }
    const int nq = N * 16;   // N*64/4
    for (int i = gid; i < nq; i += gsz) {
        float4 v = ((const float4*)feat)[i];
        unsigned ux = __float_as_uint(v.x), uy = __float_as_uint(v.y);
        unsigned uz = __float_as_uint(v.z), uw = __float_as_uint(v.w);
        ushort4 hh;
        hh.x = (unsigned short)((ux + 0x7FFFu + ((ux >> 16) & 1u)) >> 16);
        hh.y = (unsigned short)((uy + 0x7FFFu + ((uy >> 16) & 1u)) >> 16);
        hh.z = (unsigned short)((uz + 0x7FFFu + ((uz >> 16) & 1u)) >> 16);
        hh.w = (unsigned short)((uw + 0x7FFFu + ((uw >> 16) & 1u)) >> 16);
        ((ushort4*)featH)[i] = hh;
    }
    for (int i = gid; i < N; i += gsz)
        loc4[i] = make_float4(loc[3 * i], loc[3 * i + 1], loc[3 * i + 2], 0.f);
}

// ---------------- K2: merge+scan fused (49 blocks x 1024, matches co[d>>10]) ----------------

__global__ __launch_bounds__(1024) void merge_scan_kernel(
    unsigned char* __restrict__ pcnt, const unsigned char* __restrict__ psrc,
    int* __restrict__ cnt, float* __restrict__ d2w,
    int* __restrict__ startv, int* __restrict__ part, int P, int N) {

    __shared__ int wsum[16];
    const int t = threadIdx.x, lane = t & 63, wv = t >> 6;
    const int d = blockIdx.x * 1024 + t;

    int sc = 0;
    if (d < N) {
        #pragma unroll 4
        for (int p = 0; p < P; ++p) {
            const size_t idx = (size_t)p * NBINS + d;
            const int c = pcnt[idx];
            pcnt[idx] = (unsigned char)sc;
            sc += c;
        }
        cnt[d] = sc;
        int ss = 0;
        #pragma unroll 4
        for (int p = 0; p < P; ++p) ss += psrc[(size_t)p * NBINS + d];
        d2w[d] = rsqrtf(fmaxf((float)ss, 1.0f));
    }

    const int v = sc;          // 0 for d >= N
    int x = v;
    #pragma unroll
    for (int off = 1; off < 64; off <<= 1) { int y = __shfl_up(x, off); if (lane >= off) x += y; }
    if (lane == 63) wsum[wv] = x;
    __syncthreads();
    if (t < 16) {
        int w = wsum[t], xx = w;
        #pragma unroll
        for (int off = 1; off < 16; off <<= 1) { int y = __shfl_up(xx, off); if (t >= off) xx += y; }
        wsum[t] = xx - w;
    }
    __syncthreads();
    int incl = x + wsum[wv];
    if (d < N) startv[d] = incl - v;
    if (t == 1023) part[blockIdx.x] = incl;
}

// shared helper: chunk-offset prefix (nb <= 64) into smem
__device__ __forceinline__ void load_chunkoff(const int* __restrict__ part, int nb,
                                              int* __restrict__ co) {
    if (threadIdx.x < 64) {
        int v = (threadIdx.x < nb) ? part[threadIdx.x] : 0;
        int x = v;
        #pragma unroll
        for (int off = 1; off < 64; off <<= 1) {
            int y = __shfl_up(x, off);
            if ((threadIdx.x & 63) >= off) x += y;
        }
        co[threadIdx.x] = x - v;                 // exclusive
    }
    __syncthreads();
}

// ---------------- K3: edge — 4 edges/thread, phase-separated branchless loads (r13) ---------

__global__ __launch_bounds__(256) void edge_kernel(
    const float4* __restrict__ loc4, const float* __restrict__ boundaries,
    const int* __restrict__ lut,
    const int* __restrict__ src, const int* __restrict__ dst,
    const int* __restrict__ inter,
    const unsigned char* __restrict__ rnk8, const unsigned char* __restrict__ pcnt,
    const int* __restrict__ startv, const int* __restrict__ part,
    const float* __restrict__ d2w,
    int4* __restrict__ rec, int E, int nb) {

    __shared__ int lut_s[LUTN];
    __shared__ float bl[64];
    __shared__ int co[64];
    ((int4*)lut_s)[threadIdx.x] = ((const int4*)lut)[threadIdx.x];
    if (threadIdx.x < 64)
        bl[threadIdx.x] = (threadIdx.x < 63) ? boundaries[threadIdx.x] : 3.4e38f;
    load_chunkoff(part, nb, co);   // its __syncthreads also covers lut_s/bl

    const int ebase = blockIdx.x * 1024 + threadIdx.x;

    // ---- phase 1: coalesced id loads (clamped; always valid) ----
    int  eA[4], sA[4], dA[4];
    int4 iiA[4];
    #pragma unroll
    for (int u = 0; u < 4; ++u) {
        const int e  = ebase + u * 256;
        const int ec = (e < E) ? e : (E - 1);
        eA[u] = e;
        sA[u] = src[ec];
        dA[u] = dst[ec];
        iiA[u] = ((const int4*)inter)[ec];
    }

    // ---- phase 2: issue all position gathers (24 independent loads) ----
    float4 psA[4], pdA[4], ptA[4][4];
    #pragma unroll
    for (int u = 0; u < 4; ++u) {
        psA[u]    = loc4[sA[u]];
        pdA[u]    = loc4[dA[u]];
        ptA[u][0] = loc4[iiA[u].x];
        ptA[u][1] = loc4[iiA[u].y];
        ptA[u][2] = loc4[iiA[u].z];
        ptA[u][3] = loc4[iiA[u].w];
    }

    // ---- phase 3: placement metadata (12 independent loads) ----
    int cb[4], rk[4];
    float wv[4];
    #pragma unroll
    for (int u = 0; u < 4; ++u) {
        const int ec = (eA[u] < E) ? eA[u] : (E - 1);
        cb[u] = pcnt[(size_t)(ec >> CHSH) * NBINS + dA[u]];
        rk[u] = rnk8[ec];
        wv[u] = d2w[sA[u]];
    }

    // ---- phase 4: compute + masked store ----
    #pragma unroll
    for (int u = 0; u < 4; ++u) {
        float dist[5];
        {
            float dx = pdA[u].x - psA[u].x, dy = pdA[u].y - psA[u].y, dz = pdA[u].z - psA[u].z;
            dist[0] = sqrtf(dx * dx + dy * dy + dz * dz);
        }
        #pragma unroll
        for (int j = 0; j < 4; ++j) {
            float dx = ptA[u][j].x - psA[u].x, dy = ptA[u][j].y - psA[u].y,
                  dz = ptA[u][j].z - psA[u].z;
            dist[1 + j] = sqrtf(dx * dx + dy * dy + dz * dz);
        }
        unsigned pack = 0;
        #pragma unroll
        for (int q = 0; q < 5; ++q) {
            float dq = dist[q];
            int cell = (int)(dq * LUTSCALE);
            cell = (cell > LUTN - 1) ? (LUTN - 1) : cell;
            int b = lut_s[cell];
            while (b < 63 && bl[b] < dq) ++b;
            while (b > 0 && bl[b - 1] >= dq) --b;
            pack |= ((unsigned)b) << (6 * q);
        }

        if (eA[u] < E) {
            const int pos = startv[dA[u]] + co[dA[u] >> 10] + cb[u] + rk[u];
            unsigned uw = __float_as_uint(wv[u]);
            unsigned wb = (uw + 0x7FFFu + ((uw >> 16) & 1u)) & 0xFFFF0000u;  // bf16 hi half
            rec[pos] = make_int4(sA[u] | (iiA[u].x << 16), iiA[u].y | (iiA[u].z << 16),
                                 iiA[u].w | (int)wb, (int)pack);
        }
    }
}

// ---------------- K4: wave-per-node gather (EXACT r3 form — empirical floor ~52 us) ---------

__global__ __launch_bounds__(256) void node_kernel(
    const unsigned short* __restrict__ featH, const float* __restrict__ M,
    const int* __restrict__ cnt, const int* __restrict__ startv,
    const int* __restrict__ part, const int4* __restrict__ rec,
    float* __restrict__ cat, float* __restrict__ swb, int N, int nb) {

    __shared__ float Ms[4096];
    __shared__ int co[64];
    #pragma unroll
    for (int i = 0; i < 4; ++i)
        ((float4*)Ms)[threadIdx.x + 256 * i] = ((const float4*)M)[threadIdx.x + 256 * i];
    load_chunkoff(part, nb, co);   // includes the __syncthreads for Ms too

    const int lane = threadIdx.x & 63;
    const int wid  = threadIdx.x >> 6;
    const int d    = blockIdx.x * 4 + wid;
    if (d >= N) return;

    const int deg  = __builtin_amdgcn_readfirstlane(cnt[d]);
    const int base = __builtin_amdgcn_readfirstlane(startv[d] + co[d >> 10]);
    const int4* rp = rec + base;

    float acc0 = 0.f, acc1 = 0.f, sw = 0.f;

    #pragma unroll 4
    for (int k = 0; k < deg; ++k) {
        const int4 r = rp[k];                       // wave-uniform
        const int s  = r.x & 0xFFFF;
        const int i0 = ((unsigned)r.x) >> 16;
        const int i1 = r.y & 0xFFFF;
        const int i2 = ((unsigned)r.y) >> 16;
        const int i3 = r.z & 0xFFFF;
        const float w = __uint_as_float((unsigned)r.z & 0xFFFF0000u);
        const unsigned pk = (unsigned)r.w;

        const float fs = __uint_as_float(((unsigned)featH[(size_t)s  * 64 + lane]) << 16);
        const float f0 = __uint_as_float(((unsigned)featH[(size_t)i0 * 64 + lane]) << 16);
        const float f1 = __uint_as_float(((unsigned)featH[(size_t)i1 * 64 + lane]) << 16);
        const float f2 = __uint_as_float(((unsigned)featH[(size_t)i2 * 64 + lane]) << 16);
        const float f3 = __uint_as_float(((unsigned)featH[(size_t)i3 * 64 + lane]) << 16);
        const float m0 = Ms[(pk & 63u) * 64 + lane];
        const float m1 = Ms[((pk >> 6) & 63u) * 64 + lane];
        const float m2 = Ms[((pk >> 12) & 63u) * 64 + lane];
        const float m3 = Ms[((pk >> 18) & 63u) * 64 + lane];
        const float m4 = Ms[((pk >> 24) & 63u) * 64 + lane];

        acc0 = fmaf(m0 * fs, w, acc0);
        float t = m1 * f0 + m2 * f1 + m3 * f2 + m4 * f3;
        acc1 = fmaf(0.25f * t, w, acc1);
        sw += w;
    }

    cat[(size_t)d * 128 + lane]      = acc0;
    cat[(size_t)d * 128 + 64 + lane] = acc1;
    if (lane == 0) swb[d] = sw;
}

// ---------------- K5: epilogue GEMM — weights IN REGISTERS, no LDS in the loop --------------
// r15 learned: any LDS-staged epilogue is LDS-pipe-bound (1.6 GB through LDS >= 23 us).
// r14 learned: default regalloc would not keep aw[32] float4 resident (VGPR 72 -> spill or
// per-node remat). Fix: __launch_bounds__(256, 2) raises the VGPR budget to 256 (demand
// ~166, fits); grid 512 = 2048 waves exactly resident at 2 waves/SIMD, aw loaded once per
// wave and amortized over ~24 nodes; cat read is wave-uniform (scalar/broadcast path).

__global__ __launch_bounds__(256, 2) void epilogue_kernel(
    const float* __restrict__ cat, const float* __restrict__ agg_w,
    const float* __restrict__ agg_b, const float* __restrict__ swb,
    const int* __restrict__ cnt, float* __restrict__ out, int N) {

    const int lane = threadIdx.x & 63;
    const int wid  = threadIdx.x >> 6;

    float4 aw[32];
    const float4* awp = (const float4*)(agg_w + (size_t)lane * 128);
    #pragma unroll
    for (int i = 0; i < 32; ++i) aw[i] = awp[i];
    const float bias = agg_b[lane];

    const int gw = blockIdx.x * 4 + wid;
    const int stride = gridDim.x * 4;

    for (int d0i = gw; d0i < N; d0i += stride) {
        const int du = __builtin_amdgcn_readfirstlane(d0i);
        const float4* cp = (const float4*)(cat + (size_t)du * 128);   // wave-uniform

        float a0 = 0.f, a1 = 0.f, a2 = 0.f, a3 = 0.f;
        #pragma unroll
        for (int k4 = 0; k4 < 32; ++k4) {
            const float4 c = cp[k4];
            a0 = fmaf(aw[k4].x, c.x, a0);
            a1 = fmaf(aw[k4].y, c.y, a1);
            a2 = fmaf(aw[k4].z, c.z, a2);
            a3 = fmaf(aw[k4].w, c.w, a3);
        }
        const float d0v = rsqrtf(fmaxf((float)cnt[du], 1.0f));
        out[(size_t)du * 64 + lane] = d0v * (((a0 + a1) + (a2 + a3)) + bias * swb[du]);
    }
}

// ---------------- launch ----------------

extern "C" void kernel_launch(void* const* d_in, const int* in_sizes, int n_in,
                              void* d_out, int out_size, void* d_ws, size_t ws_size,
                              hipStream_t stream) {
    const float* feat       = (const float*)d_in[0];
    const float* loc        = (const float*)d_in[1];
    const float* boundaries = (const float*)d_in[2];
    const float* embed      = (const float*)d_in[3];
    const float* G_w        = (const float*)d_in[4];
    const float* agg_w      = (const float*)d_in[5];
    const float* agg_b      = (const float*)d_in[6];
    const int*   src        = (const int*)d_in[7];
    const int*   dst        = (const int*)d_in[8];
    const int*   inter      = (const int*)d_in[9];

    const int N = in_sizes[0] / 64;   // 50000 (< 2^16 for id packing; <= NBINS for LDS hist)
    const int E = in_sizes[7];        // 500000

    const int P = (E + (1 << CHSH) - 1) >> CHSH;   // 31 histogram chunks

    char* w = (char*)d_ws;
    auto take = [&](size_t bytes) { char* p = w; w += (bytes + 15) & ~(size_t)15; return p; };
    float*          M      = (float*)take(4096 * 4);
    int*            lut    = (int*)  take(LUTN * 4);
    int*            cnt    = (int*)  take((size_t)N * 4);
    int*            startv = (int*)  take((size_t)N * 4);
    int*            part   = (int*)  take(64 * 4);
    float*          d2w    = (float*)take((size_t)N * 4);
    int4*           rec    = (int4*) take((size_t)E * 16);
    unsigned char*  rnk8   = (unsigned char*)take((size_t)E);
    unsigned char*  pcnt   = (unsigned char*)take((size_t)P * NBINS);
    unsigned char*  psrc   = (unsigned char*)take((size_t)P * NBINS);
    float*          cat    = (float*)take((size_t)N * 128 * 4);
    float*          swb    = (float*)take((size_t)N * 4);
    unsigned short* featH  = (unsigned short*)take((size_t)N * 64 * 2);
    float4*         loc4   = (float4*)take((size_t)N * 16);
    float*          out    = (float*)d_out;

    const int eb4 = (E + 1023) / 1024;  // 489 edge blocks (4 edges/thread)
    const int nb  = (N + 1023) / 1024;  // 49 (<= 64 required by chunkoff helper)
    const int PREPB = 256;              // prep-role blocks in front_kernel (512 thr each)

    front_kernel<<<2 * P + PREPB, 512, 0, stream>>>(embed, G_w, boundaries, feat, loc,
                                                    src, dst, M, lut, featH, loc4,
                                                    pcnt, psrc, rnk8, N, E, P, PREPB);
    merge_scan_kernel<<<nb, 1024, 0, stream>>>(pcnt, psrc, cnt, d2w, startv, part, P, N);
    edge_kernel<<<eb4, 256, 0, stream>>>(loc4, boundaries, lut, src, dst, inter,
                                         rnk8, pcnt, startv, part, d2w, rec, E, nb);
    node_kernel<<<(N + 3) / 4, 256, 0, stream>>>(featH, M, cnt, startv, part, rec,
                                                 cat, swb, N, nb);
    epilogue_kernel<<<512, 256, 0, stream>>>(cat, agg_w, agg_b, swb, cnt, out, N);
}

// Round 17
// 210.119 us; speedup vs baseline: 1.0979x; 1.0979x over previous
//
#include <hip/hip_runtime.h>
#include <math.h>

#define LUTN 1024
#define LUTSCALE 512.0f
#define NBINS 50048        // >= N, multiple of 4 (uchar-packed LDS histogram width)
#define CHSH 14            // edge chunk = 16384 edges per histogram block pair (P=31)
                           // per-chunk per-bin count ~Poisson(0.33), max ~8 << 255: uchar safe

// ---------------- K1: front — fused roles: hist blocks [0,2P) + prep blocks [2P,2P+PREPB) ---
// hist role: block 2p = dst hist + rank of chunk p -> pcnt/rnk8; 2p+1 = src hist -> psrc.
// prep role: M table, LUT, feat->bf16, loc->float4. Independent inputs, no cross-role deps.

__global__ __launch_bounds__(512) void front_kernel(
    const float* __restrict__ embed, const float* __restrict__ G_w,
    const float* __restrict__ boundaries, const float* __restrict__ feat,
    const float* __restrict__ loc,
    const int* __restrict__ src, const int* __restrict__ dst,
    float* __restrict__ M, int* __restrict__ lut,
    unsigned short* __restrict__ featH, float4* __restrict__ loc4,
    unsigned char* __restrict__ pcnt, unsigned char* __restrict__ psrc,
    unsigned char* __restrict__ rnk8,
    int N, int E, int P, int PREPB) {

    __shared__ unsigned int h[NBINS / 4];   // 50 KB (hist roles only; prep ignores)

    if (blockIdx.x < 2 * P) {
        for (int i = threadIdx.x; i < NBINS / 4; i += 512) h[i] = 0u;
        __syncthreads();

        const int p    = blockIdx.x >> 1;
        const int role = blockIdx.x & 1;
        const int base = p << CHSH;
        const int lim  = min(E - base, 1 << CHSH);

        if (role == 0) {
            for (int t = threadIdx.x; t < lim; t += 512) {
                const int e = base + t;
                const int d = dst[e];
                const unsigned sh = (unsigned)(d & 3) * 8u;
                unsigned old = atomicAdd(&h[d >> 2], 1u << sh);
                rnk8[e] = (unsigned char)((old >> sh) & 0xFFu);
            }
            __syncthreads();
            unsigned int* gc = (unsigned int*)(pcnt + (size_t)p * NBINS);
            for (int i = threadIdx.x; i < NBINS / 4; i += 512) gc[i] = h[i];
        } else {
            for (int t = threadIdx.x; t < lim; t += 512) {
                const int s = src[base + t];
                atomicAdd(&h[s >> 2], 1u << ((unsigned)(s & 3) * 8u));
            }
            __syncthreads();
            unsigned int* gs = (unsigned int*)(psrc + (size_t)p * NBINS);
            for (int i = threadIdx.x; i < NBINS / 4; i += 512) gs[i] = h[i];
        }
        return;
    }

    // ---- prep role ----
    const int gid = (blockIdx.x - 2 * P) * 512 + threadIdx.x;
    const int gsz = PREPB * 512;
    for (int i = gid; i < 4096; i += gsz) {
        int b = i >> 6, f = i & 63;
        float acc = 0.f;
        #pragma unroll
        for (int dd = 0; dd < 32; ++dd) acc += embed[b * 32 + dd] * G_w[f * 32 + dd];
        M[i] = acc;
    }
    for (int i = gid; i < LUTN; i += gsz) {
        float left = (float)i * (1.0f / LUTSCALE);
        int c = 0;
        for (int j = 0; j < 63; ++j) c += (boundaries[j] < left) ? 1 : 0;
        lut[i] = c;
    }
    const int nq = N * 16;   // N*64/4
    for (int i = gid; i < nq; i += gsz) {
        float4 v = ((const float4*)feat)[i];
        unsigned ux = __float_as_uint(v.x), uy = __float_as_uint(v.y);
        unsigned uz = __float_as_uint(v.z), uw = __float_as_uint(v.w);
        ushort4 hh;
        hh.x = (unsigned short)((ux + 0x7FFFu + ((ux >> 16) & 1u)) >> 16);
        hh.y = (unsigned short)((uy + 0x7FFFu + ((uy >> 16) & 1u)) >> 16);
        hh.z = (unsigned short)((uz + 0x7FFFu + ((uz >> 16) & 1u)) >> 16);
        hh.w = (unsigned short)((uw + 0x7FFFu + ((uw >> 16) & 1u)) >> 16);
        ((ushort4*)featH)[i] = hh;
    }
    for (int i = gid; i < N; i += gsz)
        loc4[i] = make_float4(loc[3 * i], loc[3 * i + 1], loc[3 * i + 2], 0.f);
}

// ---------------- K2: merge+scan fused (49 blocks x 1024, matches co[d>>10]) ----------------

__global__ __launch_bounds__(1024) void merge_scan_kernel(
    unsigned char* __restrict__ pcnt, const unsigned char* __restrict__ psrc,
    int* __restrict__ cnt, float* __restrict__ d2w,
    int* __restrict__ startv, int* __restrict__ part, int P, int N) {

    __shared__ int wsum[16];
    const int t = threadIdx.x, lane = t & 63, wv = t >> 6;
    const int d = blockIdx.x * 1024 + t;

    int sc = 0;
    if (d < N) {
        #pragma unroll 4
        for (int p = 0; p < P; ++p) {
            const size_t idx = (size_t)p * NBINS + d;
            const int c = pcnt[idx];
            pcnt[idx] = (unsigned char)sc;
            sc += c;
        }
        cnt[d] = sc;
        int ss = 0;
        #pragma unroll 4
        for (int p = 0; p < P; ++p) ss += psrc[(size_t)p * NBINS + d];
        d2w[d] = rsqrtf(fmaxf((float)ss, 1.0f));
    }

    const int v = sc;          // 0 for d >= N
    int x = v;
    #pragma unroll
    for (int off = 1; off < 64; off <<= 1) { int y = __shfl_up(x, off); if (lane >= off) x += y; }
    if (lane == 63) wsum[wv] = x;
    __syncthreads();
    if (t < 16) {
        int w = wsum[t], xx = w;
        #pragma unroll
        for (int off = 1; off < 16; off <<= 1) { int y = __shfl_up(xx, off); if (t >= off) xx += y; }
        wsum[t] = xx - w;
    }
    __syncthreads();
    int incl = x + wsum[wv];
    if (d < N) startv[d] = incl - v;
    if (t == 1023) part[blockIdx.x] = incl;
}

// shared helper: chunk-offset prefix (nb <= 64) into smem
__device__ __forceinline__ void load_chunkoff(const int* __restrict__ part, int nb,
                                              int* __restrict__ co) {
    if (threadIdx.x < 64) {
        int v = (threadIdx.x < nb) ? part[threadIdx.x] : 0;
        int x = v;
        #pragma unroll
        for (int off = 1; off < 64; off <<= 1) {
            int y = __shfl_up(x, off);
            if ((threadIdx.x & 63) >= off) x += y;
        }
        co[threadIdx.x] = x - v;                 // exclusive
    }
    __syncthreads();
}

// ---------------- K3: edge — 4 edges/thread, phase-separated branchless loads (r13) ---------

__global__ __launch_bounds__(256) void edge_kernel(
    const float4* __restrict__ loc4, const float* __restrict__ boundaries,
    const int* __restrict__ lut,
    const int* __restrict__ src, const int* __restrict__ dst,
    const int* __restrict__ inter,
    const unsigned char* __restrict__ rnk8, const unsigned char* __restrict__ pcnt,
    const int* __restrict__ startv, const int* __restrict__ part,
    const float* __restrict__ d2w,
    int4* __restrict__ rec, int E, int nb) {

    __shared__ int lut_s[LUTN];
    __shared__ float bl[64];
    __shared__ int co[64];
    ((int4*)lut_s)[threadIdx.x] = ((const int4*)lut)[threadIdx.x];
    if (threadIdx.x < 64)
        bl[threadIdx.x] = (threadIdx.x < 63) ? boundaries[threadIdx.x] : 3.4e38f;
    load_chunkoff(part, nb, co);   // its __syncthreads also covers lut_s/bl

    const int ebase = blockIdx.x * 1024 + threadIdx.x;

    // ---- phase 1: coalesced id loads (clamped; always valid) ----
    int  eA[4], sA[4], dA[4];
    int4 iiA[4];
    #pragma unroll
    for (int u = 0; u < 4; ++u) {
        const int e  = ebase + u * 256;
        const int ec = (e < E) ? e : (E - 1);
        eA[u] = e;
        sA[u] = src[ec];
        dA[u] = dst[ec];
        iiA[u] = ((const int4*)inter)[ec];
    }

    // ---- phase 2: issue all position gathers (24 independent loads) ----
    float4 psA[4], pdA[4], ptA[4][4];
    #pragma unroll
    for (int u = 0; u < 4; ++u) {
        psA[u]    = loc4[sA[u]];
        pdA[u]    = loc4[dA[u]];
        ptA[u][0] = loc4[iiA[u].x];
        ptA[u][1] = loc4[iiA[u].y];
        ptA[u][2] = loc4[iiA[u].z];
        ptA[u][3] = loc4[iiA[u].w];
    }

    // ---- phase 3: placement metadata (12 independent loads) ----
    int cb[4], rk[4];
    float wv[4];
    #pragma unroll
    for (int u = 0; u < 4; ++u) {
        const int ec = (eA[u] < E) ? eA[u] : (E - 1);
        cb[u] = pcnt[(size_t)(ec >> CHSH) * NBINS + dA[u]];
        rk[u] = rnk8[ec];
        wv[u] = d2w[sA[u]];
    }

    // ---- phase 4: compute + masked store ----
    #pragma unroll
    for (int u = 0; u < 4; ++u) {
        float dist[5];
        {
            float dx = pdA[u].x - psA[u].x, dy = pdA[u].y - psA[u].y, dz = pdA[u].z - psA[u].z;
            dist[0] = sqrtf(dx * dx + dy * dy + dz * dz);
        }
        #pragma unroll
        for (int j = 0; j < 4; ++j) {
            float dx = ptA[u][j].x - psA[u].x, dy = ptA[u][j].y - psA[u].y,
                  dz = ptA[u][j].z - psA[u].z;
            dist[1 + j] = sqrtf(dx * dx + dy * dy + dz * dz);
        }
        unsigned pack = 0;
        #pragma unroll
        for (int q = 0; q < 5; ++q) {
            float dq = dist[q];
            int cell = (int)(dq * LUTSCALE);
            cell = (cell > LUTN - 1) ? (LUTN - 1) : cell;
            int b = lut_s[cell];
            while (b < 63 && bl[b] < dq) ++b;
            while (b > 0 && bl[b - 1] >= dq) --b;
            pack |= ((unsigned)b) << (6 * q);
        }

        if (eA[u] < E) {
            const int pos = startv[dA[u]] + co[dA[u] >> 10] + cb[u] + rk[u];
            unsigned uw = __float_as_uint(wv[u]);
            unsigned wb = (uw + 0x7FFFu + ((uw >> 16) & 1u)) & 0xFFFF0000u;  // bf16 hi half
            rec[pos] = make_int4(sA[u] | (iiA[u].x << 16), iiA[u].y | (iiA[u].z << 16),
                                 iiA[u].w | (int)wb, (int)pack);
        }
    }
}

// ---------------- K4: wave-per-node gather (EXACT r3 form — empirical floor ~52 us) ---------

__global__ __launch_bounds__(256) void node_kernel(
    const unsigned short* __restrict__ featH, const float* __restrict__ M,
    const int* __restrict__ cnt, const int* __restrict__ startv,
    const int* __restrict__ part, const int4* __restrict__ rec,
    float* __restrict__ cat, float* __restrict__ swb, int N, int nb) {

    __shared__ float Ms[4096];
    __shared__ int co[64];
    #pragma unroll
    for (int i = 0; i < 4; ++i)
        ((float4*)Ms)[threadIdx.x + 256 * i] = ((const float4*)M)[threadIdx.x + 256 * i];
    load_chunkoff(part, nb, co);   // includes the __syncthreads for Ms too

    const int lane = threadIdx.x & 63;
    const int wid  = threadIdx.x >> 6;
    const int d    = blockIdx.x * 4 + wid;
    if (d >= N) return;

    const int deg  = __builtin_amdgcn_readfirstlane(cnt[d]);
    const int base = __builtin_amdgcn_readfirstlane(startv[d] + co[d >> 10]);
    const int4* rp = rec + base;

    float acc0 = 0.f, acc1 = 0.f, sw = 0.f;

    #pragma unroll 4
    for (int k = 0; k < deg; ++k) {
        const int4 r = rp[k];                       // wave-uniform
        const int s  = r.x & 0xFFFF;
        const int i0 = ((unsigned)r.x) >> 16;
        const int i1 = r.y & 0xFFFF;
        const int i2 = ((unsigned)r.y) >> 16;
        const int i3 = r.z & 0xFFFF;
        const float w = __uint_as_float((unsigned)r.z & 0xFFFF0000u);
        const unsigned pk = (unsigned)r.w;

        const float fs = __uint_as_float(((unsigned)featH[(size_t)s  * 64 + lane]) << 16);
        const float f0 = __uint_as_float(((unsigned)featH[(size_t)i0 * 64 + lane]) << 16);
        const float f1 = __uint_as_float(((unsigned)featH[(size_t)i1 * 64 + lane]) << 16);
        const float f2 = __uint_as_float(((unsigned)featH[(size_t)i2 * 64 + lane]) << 16);
        const float f3 = __uint_as_float(((unsigned)featH[(size_t)i3 * 64 + lane]) << 16);
        const float m0 = Ms[(pk & 63u) * 64 + lane];
        const float m1 = Ms[((pk >> 6) & 63u) * 64 + lane];
        const float m2 = Ms[((pk >> 12) & 63u) * 64 + lane];
        const float m3 = Ms[((pk >> 18) & 63u) * 64 + lane];
        const float m4 = Ms[((pk >> 24) & 63u) * 64 + lane];

        acc0 = fmaf(m0 * fs, w, acc0);
        float t = m1 * f0 + m2 * f1 + m3 * f2 + m4 * f3;
        acc1 = fmaf(0.25f * t, w, acc1);
        sw += w;
    }

    cat[(size_t)d * 128 + lane]      = acc0;
    cat[(size_t)d * 128 + 64 + lane] = acc1;
    if (lane == 0) swb[d] = sw;
}

// ---------------- K5: epilogue GEMM — LDS weights amortized over 8 nodes/wave ---------------
// r15 learned: LDS epilogue is LDS-pipe-bound (128 awT b32 reads/lane/node = 1.6 GB).
// r14/r16 learned (twice): compiler will NOT keep a 128-VGPR aw tile resident. Fix: keep awT
// in LDS but process 8 nodes per wave pass -> each awT read feeds 8 fmaf (aw reads/node
// 128 -> 16; LDS ops/node 160 -> 48). cr broadcasts are same-address (conflict-free);
// awT stride-65 conflict-free. 49 KB LDS -> 3 blocks/CU.

__global__ __launch_bounds__(256) void epilogue_kernel(
    const float* __restrict__ cat, const float* __restrict__ agg_w,
    const float* __restrict__ agg_b, const float* __restrict__ swb,
    const int* __restrict__ cnt, float* __restrict__ out, int N) {

    __shared__ float awT[128 * 65];      // 33.3 KB transposed weights
    __shared__ float cr[4][8][128];      // 16 KB: per-wave 8 cat rows

    for (int i = threadIdx.x; i < 8192; i += 256) {
        const int f = i >> 7, k = i & 127;
        awT[k * 65 + f] = agg_w[i];      // read coalesced; write conflict-free (stride 65)
    }
    __syncthreads();

    const int lane = threadIdx.x & 63;
    const int wid  = threadIdx.x >> 6;
    const float bias = agg_b[lane];

    const int g  = blockIdx.x * 4 + wid;   // node-group id (8 nodes per group)
    const int d0 = g * 8;
    if (d0 >= N) return;

    // stage 8 cat rows (coalesced float2/lane each; clamped for tail)
    #pragma unroll
    for (int j = 0; j < 8; ++j) {
        const int d  = d0 + j;
        const int dc = (d < N) ? d : (N - 1);
        *(float2*)&cr[wid][j][2 * lane] =
            *(const float2*)(cat + (size_t)dc * 128 + 2 * lane);
    }
    // intra-wave LDS write->read: compiler orders via lgkmcnt (proven in r15)

    float4 acc[8];
    #pragma unroll
    for (int j = 0; j < 8; ++j) acc[j] = make_float4(0.f, 0.f, 0.f, 0.f);

    for (int k = 0; k < 128; k += 4) {
        const float w0 = awT[(k + 0) * 65 + lane];
        const float w1 = awT[(k + 1) * 65 + lane];
        const float w2 = awT[(k + 2) * 65 + lane];
        const float w3 = awT[(k + 3) * 65 + lane];
        #pragma unroll
        for (int j = 0; j < 8; ++j) {
            const float4 c = *(const float4*)&cr[wid][j][k];   // broadcast read
            acc[j].x = fmaf(w0, c.x, acc[j].x);
            acc[j].y = fmaf(w1, c.y, acc[j].y);
            acc[j].z = fmaf(w2, c.z, acc[j].z);
            acc[j].w = fmaf(w3, c.w, acc[j].w);
        }
    }

    #pragma unroll
    for (int j = 0; j < 8; ++j) {
        const int d = d0 + j;
        if (d < N) {
            const float d0v = rsqrtf(fmaxf((float)cnt[d], 1.0f));
            out[(size_t)d * 64 + lane] =
                d0v * (((acc[j].x + acc[j].y) + (acc[j].z + acc[j].w)) + bias * swb[d]);
        }
    }
}

// ---------------- launch ----------------

extern "C" void kernel_launch(void* const* d_in, const int* in_sizes, int n_in,
                              void* d_out, int out_size, void* d_ws, size_t ws_size,
                              hipStream_t stream) {
    const float* feat       = (const float*)d_in[0];
    const float* loc        = (const float*)d_in[1];
    const float* boundaries = (const float*)d_in[2];
    const float* embed      = (const float*)d_in[3];
    const float* G_w        = (const float*)d_in[4];
    const float* agg_w      = (const float*)d_in[5];
    const float* agg_b      = (const float*)d_in[6];
    const int*   src        = (const int*)d_in[7];
    const int*   dst        = (const int*)d_in[8];
    const int*   inter      = (const int*)d_in[9];

    const int N = in_sizes[0] / 64;   // 50000 (< 2^16 for id packing; <= NBINS for LDS hist)
    const int E = in_sizes[7];        // 500000

    const int P = (E + (1 << CHSH) - 1) >> CHSH;   // 31 histogram chunks

    char* w = (char*)d_ws;
    auto take = [&](size_t bytes) { char* p = w; w += (bytes + 15) & ~(size_t)15; return p; };
    float*          M      = (float*)take(4096 * 4);
    int*            lut    = (int*)  take(LUTN * 4);
    int*            cnt    = (int*)  take((size_t)N * 4);
    int*            startv = (int*)  take((size_t)N * 4);
    int*            part   = (int*)  take(64 * 4);
    float*          d2w    = (float*)take((size_t)N * 4);
    int4*           rec    = (int4*) take((size_t)E * 16);
    unsigned char*  rnk8   = (unsigned char*)take((size_t)E);
    unsigned char*  pcnt   = (unsigned char*)take((size_t)P * NBINS);
    unsigned char*  psrc   = (unsigned char*)take((size_t)P * NBINS);
    float*          cat    = (float*)take((size_t)N * 128 * 4);
    float*          swb    = (float*)take((size_t)N * 4);
    unsigned short* featH  = (unsigned short*)take((size_t)N * 64 * 2);
    float4*         loc4   = (float4*)take((size_t)N * 16);
    float*          out    = (float*)d_out;

    const int eb4 = (E + 1023) / 1024;  // 489 edge blocks (4 edges/thread)
    const int nb  = (N + 1023) / 1024;  // 49 (<= 64 required by chunkoff helper)
    const int PREPB = 256;              // prep-role blocks in front_kernel (512 thr each)
    const int epb = ((N + 7) / 8 + 3) / 4;   // 1563 epilogue blocks (4 waves x 8 nodes)

    front_kernel<<<2 * P + PREPB, 512, 0, stream>>>(embed, G_w, boundaries, feat, loc,
                                                    src, dst, M, lut, featH, loc4,
                                                    pcnt, psrc, rnk8, N, E, P, PREPB);
    merge_scan_kernel<<<nb, 1024, 0, stream>>>(pcnt, psrc, cnt, d2w, startv, part, P, N);
    edge_kernel<<<eb4, 256, 0, stream>>>(loc4, boundaries, lut, src, dst, inter,
                                         rnk8, pcnt, startv, part, d2w, rec, E, nb);
    node_kernel<<<(N + 3) / 4, 256, 0, stream>>>(featH, M, cnt, startv, part, rec,
                                                 cat, swb, N, nb);
    epilogue_kernel<<<epb, 256, 0, stream>>>(cat, agg_w, agg_b, swb, cnt, out, N);
}